// Round 1
// 3230.816 us; speedup vs baseline: 1.1996x; 1.1996x over previous
//
#include <hip/hip_runtime.h>
#include <hip/hip_bf16.h>
#include <type_traits>

// ViT-Base/16 forward. Round 4: triple-buffered global_load_lds prefetch
// pipeline in bgemm (counted vmcnt, raw s_barrier — never drain vmcnt in the
// K-loop). Attn unchanged this round.

#define BV   32
#define DIM  768
#define NHD  12
#define DH   64
#define NSEQ 197
#define NPAT 196
#define MLPD 3072
#define NCLS 1000
#define NLAYER 12

typedef __hip_bfloat16 bf16;
typedef __attribute__((ext_vector_type(8))) short s8v;    // 8 bf16 (4 VGPRs)
typedef __attribute__((ext_vector_type(4))) float f32x4;  // MFMA acc

#define GLDS16(gp, lp) __builtin_amdgcn_global_load_lds( \
    (const __attribute__((address_space(1))) void*)(gp), \
    (__attribute__((address_space(3))) void*)(lp), 16, 0, 0)

__device__ __forceinline__ short f2bf(float v) {
    return (short)__bfloat16_as_ushort(__float2bfloat16(v));
}

// ------------------------------------------------------------- MFMA GEMM ----
// C[M,N] = epilogue(A @ B^T + bias), A: [M,K] bf16 (lda), B: [N,K] bf16 (ldb),
// both K-contiguous. TO = float or bf16. ACT=1 -> exact GELU. RESID (float
// only): C += result. K % 32 == 0. Tile 128x128, BK=32, 4 waves (2x2).
// K-loop: 3-deep LDS pipeline, tiles t+1/t+2 in flight across barriers.
template<int ACT, bool RESID, typename TO>
__global__ __launch_bounds__(256)
void bgemm(const bf16* __restrict__ A, const bf16* __restrict__ B,
           const float* __restrict__ bias, TO* __restrict__ C,
           int M, int N, int K, int lda, int ldb, int ldc)
{
    __shared__ short As[24576];   // 3 bufs x (A 4096 + B 4096) shorts = 48 KB

    // XCD-aware swizzle: balanced bijection, XCD x owns a contiguous
    // row-major tile range (shares A panels, streams B).
    int nbx = gridDim.x;
    int nb  = nbx * gridDim.y;
    int bid = blockIdx.y * nbx + blockIdx.x;
    {
        int per = nb >> 3, rem = nb & 7;
        int x = bid & 7, loc = bid >> 3;
        bid = x * per + (x < rem ? x : rem) + loc;
    }
    const int m0 = (bid / nbx) * 128;
    const int n0 = (bid % nbx) * 128;

    const int tid  = threadIdx.x;
    const int wave = tid >> 6;
    const int lane = tid & 63;

    const int c0 = wave * 2, c1 = c0 + 1;
    const int rsub = lane >> 2;
    const int kp8  = (lane & 3) * 8;

    int ra0 = m0 + c0 * 16 + rsub; if (ra0 > M - 1) ra0 = M - 1;
    int ra1 = m0 + c1 * 16 + rsub; if (ra1 > M - 1) ra1 = M - 1;
    int rb0 = n0 + c0 * 16 + rsub; if (rb0 > N - 1) rb0 = N - 1;
    int rb1 = n0 + c1 * 16 + rsub; if (rb1 > N - 1) rb1 = N - 1;

    const bf16* pa0 = A + (long)ra0 * lda + kp8;
    const bf16* pa1 = A + (long)ra1 * lda + kp8;
    const bf16* pb0 = B + (long)rb0 * ldb + kp8;
    const bf16* pb1 = B + (long)rb1 * ldb + kp8;

    const int wm = wave >> 1, wn = wave & 1;
    const int colr = lane & 15;
    const int quad = lane >> 4;

    f32x4 acc[4][4];
    #pragma unroll
    for (int i = 0; i < 4; ++i)
        #pragma unroll
        for (int j = 0; j < 4; ++j)
            acc[i][j] = (f32x4){0.f, 0.f, 0.f, 0.f};

    const short* AsP = &As[(wm * 64 + colr) * 32 + quad * 8];
    const short* BsP = &As[4096 + (wn * 64 + colr) * 32 + quad * 8];

#define STAGE(bufi) do {                              \
        int _o = (bufi) * 8192;                       \
        GLDS16(pa0, &As[_o + c0 * 512]);              \
        GLDS16(pa1, &As[_o + c1 * 512]);              \
        GLDS16(pb0, &As[_o + 4096 + c0 * 512]);       \
        GLDS16(pb1, &As[_o + 4096 + c1 * 512]);       \
        pa0 += 32; pa1 += 32; pb0 += 32; pb1 += 32;   \
    } while (0)

    const int nt = K >> 5;        // K / 32, always >= 24 here
    STAGE(0);
    STAGE(1);
    int cur = 0, nxt = 2;

    for (int t = 0; t < nt; ++t) {
        if (t + 2 < nt) {
            STAGE(nxt);
            nxt = (nxt == 2) ? 0 : nxt + 1;
            // 8 newer loads (tiles t+1, t+2) stay in flight; tile t is done.
            asm volatile("s_waitcnt vmcnt(8)" ::: "memory");
        } else if (t + 1 < nt) {
            asm volatile("s_waitcnt vmcnt(4)" ::: "memory");
        } else {
            asm volatile("s_waitcnt vmcnt(0)" ::: "memory");
        }
        __builtin_amdgcn_s_barrier();            // tile t visible to all waves
        asm volatile("" ::: "memory");

        const short* Ab = AsP + cur * 8192;
        const short* Bb = BsP + cur * 8192;
        s8v a[4], b[4];
        #pragma unroll
        for (int i = 0; i < 4; ++i) a[i] = *(const s8v*)(Ab + i * 512);
        #pragma unroll
        for (int j = 0; j < 4; ++j) b[j] = *(const s8v*)(Bb + j * 512);
        #pragma unroll
        for (int i = 0; i < 4; ++i)
            #pragma unroll
            for (int j = 0; j < 4; ++j)
                acc[i][j] = __builtin_amdgcn_mfma_f32_16x16x32_bf16(
                    a[i], b[j], acc[i][j], 0, 0, 0);

        cur = (cur == 2) ? 0 : cur + 1;
        asm volatile("" ::: "memory");
        __builtin_amdgcn_s_barrier();            // buf[cur] free to overwrite
        asm volatile("" ::: "memory");
    }
#undef STAGE

    // ---- epilogue: per-wave LDS transpose -> vectorized stores ----
    // C/D layout: col = lane&15, row = quad*4 + reg   [m89-verified]
    float* ep = ((float*)As) + wave * 1024;   // 16x64 fp32 per wave (16 KB tot)
    const int lrow = lane >> 2;
    const int lc4  = (lane & 3) * 16;

    #pragma unroll
    for (int i = 0; i < 4; ++i) {
        #pragma unroll
        for (int j = 0; j < 4; ++j)
            #pragma unroll
            for (int r = 0; r < 4; ++r)
                ep[(quad * 4 + r) * 64 + j * 16 + colr] = acc[i][j][r];
        __syncthreads();

        int gm = m0 + wm * 64 + i * 16 + lrow;
        int gn = n0 + wn * 64 + lc4;
        if (gm < M) {
            float vals[16];
            #pragma unroll
            for (int c = 0; c < 16; ++c) vals[c] = ep[lrow * 64 + lc4 + c];

            if (gn + 16 <= N) {
                if (bias) {
                    #pragma unroll
                    for (int c = 0; c < 16; ++c) vals[c] += bias[gn + c];
                }
                if (ACT == 1) {
                    #pragma unroll
                    for (int c = 0; c < 16; ++c)
                        vals[c] = 0.5f * vals[c] *
                                  (1.0f + erff(vals[c] * 0.70710678118654752f));
                }
                if constexpr (std::is_same<TO, float>::value) {
                    float* Cp = (float*)C + (long)gm * ldc + gn;
                    if constexpr (RESID) {
                        #pragma unroll
                        for (int c4 = 0; c4 < 4; ++c4) {
                            f32x4 old = *(const f32x4*)&Cp[c4 * 4];
                            #pragma unroll
                            for (int e = 0; e < 4; ++e) vals[c4 * 4 + e] += old[e];
                        }
                    }
                    #pragma unroll
                    for (int c4 = 0; c4 < 4; ++c4) {
                        f32x4 v;
                        #pragma unroll
                        for (int e = 0; e < 4; ++e) v[e] = vals[c4 * 4 + e];
                        *(f32x4*)&Cp[c4 * 4] = v;
                    }
                } else {
                    short* Cp = (short*)C + (long)gm * ldc + gn;
                    s8v v0, v1;
                    #pragma unroll
                    for (int e = 0; e < 8; ++e) { v0[e] = f2bf(vals[e]); v1[e] = f2bf(vals[8 + e]); }
                    *(s8v*)&Cp[0] = v0;
                    *(s8v*)&Cp[8] = v1;
                }
            } else {
                // partial-N fallback (head GEMM, N=1000)
                #pragma unroll
                for (int c = 0; c < 16; ++c) {
                    int g = gn + c;
                    if (g >= N) continue;
                    float v = vals[c];
                    if (bias) v += bias[g];
                    if (ACT == 1) v = 0.5f * v * (1.0f + erff(v * 0.70710678118654752f));
                    long idx = (long)gm * ldc + g;
                    if constexpr (RESID) v += ((const float*)C)[idx];
                    if constexpr (std::is_same<TO, float>::value) C[idx] = v;
                    else C[idx] = __float2bfloat16(v);
                }
            }
        }
        __syncthreads();
    }
}

// --------------------------------------------------- fused flash attention --
// One WG (4 waves) per (b, h, 64-row Q tile). qkv: [B*197][2304] bf16
// (q|k|v, head-contig 64). O: [B*197][768] bf16.
__global__ __launch_bounds__(256)
void attn_kernel(const bf16* __restrict__ qkv, bf16* __restrict__ O)
{
    __shared__ short Qs[64 * 72];    // +8 pad: kills 16-way frag-read conflicts
    __shared__ short Ks[224 * 72];   // P (64x224) overlays after S-phase
    __shared__ short Vt[64 * 224];   // V transposed [d][seq]

    const int tid  = threadIdx.x;
    const int wave = tid >> 6;
    const int lane = tid & 63;
    const int q0 = blockIdx.x * 64;
    const int b  = blockIdx.y / NHD;
    const int h  = blockIdx.y % NHD;
    const bf16* base = qkv + (long)b * NSEQ * (3 * DIM);

    // ---- stage Q (64x64), K (224x64, clamped), Vt (64x224, clamped) ----
    #pragma unroll
    for (int p = 0; p < 2; ++p) {
        int idx = p * 2048 + tid * 8;
        int row = idx >> 6, col = idx & 63;
        int gr = q0 + row; if (gr > NSEQ - 1) gr = NSEQ - 1;
        *(s8v*)&Qs[row * 72 + col] =
            *(const s8v*)&base[(long)gr * (3 * DIM) + h * DH + col];
    }
    #pragma unroll
    for (int p = 0; p < 7; ++p) {
        int idx = p * 2048 + tid * 8;
        int row = idx >> 6, col = idx & 63;
        int gr = row; if (gr > NSEQ - 1) gr = NSEQ - 1;
        *(s8v*)&Ks[row * 72 + col] =
            *(const s8v*)&base[(long)gr * (3 * DIM) + DIM + h * DH + col];
    }
    {
        int seqL = tid & 31, dc = tid >> 5;   // dc 0..7
        #pragma unroll
        for (int st = 0; st < 7; ++st) {
            int seq = st * 32 + seqL;
            int gr = seq; if (gr > NSEQ - 1) gr = NSEQ - 1;
            s8v v = *(const s8v*)&base[(long)gr * (3 * DIM) + 2 * DIM + h * DH + dc * 8];
            #pragma unroll
            for (int i = 0; i < 8; ++i)
                Vt[(dc * 8 + i) * 224 + seq] = v[i];
        }
    }
    __syncthreads();

    const int colr = lane & 15;
    const int quad = lane >> 4;

    // ---- S = Q @ K^T : each wave = 16 rows x 224 cols, K=64 ----
    f32x4 s[14];
    #pragma unroll
    for (int j = 0; j < 14; ++j) s[j] = (f32x4){0.f, 0.f, 0.f, 0.f};
    #pragma unroll
    for (int kk = 0; kk < 2; ++kk) {
        s8v a = *(const s8v*)&Qs[(wave * 16 + colr) * 72 + quad * 8 + kk * 32];
        #pragma unroll
        for (int j = 0; j < 14; ++j) {
            s8v bf = *(const s8v*)&Ks[(j * 16 + colr) * 72 + quad * 8 + kk * 32];
            s[j] = __builtin_amdgcn_mfma_f32_16x16x32_bf16(a, bf, s[j], 0, 0, 0);
        }
    }

    // ---- softmax (rows: quad*4+r within wave slice; col: j*16+colr) ----
    float mx[4] = {-1e30f, -1e30f, -1e30f, -1e30f};
    #pragma unroll
    for (int j = 0; j < 14; ++j) {
        int c = j * 16 + colr;
        #pragma unroll
        for (int r = 0; r < 4; ++r) {
            s[j][r] *= 0.125f;
            if (c < NSEQ) mx[r] = fmaxf(mx[r], s[j][r]);
        }
    }
    #pragma unroll
    for (int off = 1; off <= 8; off <<= 1)
        #pragma unroll
        for (int r = 0; r < 4; ++r)
            mx[r] = fmaxf(mx[r], __shfl_xor(mx[r], off));

    float sum[4] = {0.f, 0.f, 0.f, 0.f};
    #pragma unroll
    for (int j = 0; j < 14; ++j) {
        int c = j * 16 + colr;
        #pragma unroll
        for (int r = 0; r < 4; ++r) {
            float v = (c < NSEQ) ? expf(s[j][r] - mx[r]) : 0.f;
            s[j][r] = v;
            sum[r] += v;
        }
    }
    #pragma unroll
    for (int off = 1; off <= 8; off <<= 1)
        #pragma unroll
        for (int r = 0; r < 4; ++r)
            sum[r] += __shfl_xor(sum[r], off);
    float inv[4];
    #pragma unroll
    for (int r = 0; r < 4; ++r) inv[r] = 1.0f / sum[r];

    __syncthreads();                 // all waves done reading Ks
    short* P = Ks;                   // overlay: [64 rows][224 k] bf16
    #pragma unroll
    for (int j = 0; j < 14; ++j)
        #pragma unroll
        for (int r = 0; r < 4; ++r)
            P[(wave * 16 + quad * 4 + r) * 224 + j * 16 + colr] =
                f2bf(s[j][r] * inv[r]);

    // ---- O = P @ V : per wave 16 rows x 64 dims, K=224 ----
    f32x4 o[4];
    #pragma unroll
    for (int j2 = 0; j2 < 4; ++j2) o[j2] = (f32x4){0.f, 0.f, 0.f, 0.f};
    #pragma unroll
    for (int ks = 0; ks < 7; ++ks) {
        s8v a = *(const s8v*)&P[(wave * 16 + colr) * 224 + quad * 8 + ks * 32];
        #pragma unroll
        for (int j2 = 0; j2 < 4; ++j2) {
            s8v bf = *(const s8v*)&Vt[(j2 * 16 + colr) * 224 + quad * 8 + ks * 32];
            o[j2] = __builtin_amdgcn_mfma_f32_16x16x32_bf16(a, bf, o[j2], 0, 0, 0);
        }
    }

    #pragma unroll
    for (int j2 = 0; j2 < 4; ++j2)
        #pragma unroll
        for (int r = 0; r < 4; ++r) {
            int qrow = q0 + wave * 16 + quad * 4 + r;
            if (qrow < NSEQ)
                O[((long)b * NSEQ + qrow) * DIM + h * DH + j2 * 16 + colr] =
                    __float2bfloat16(o[j2][r]);
        }
}

// ------------------------------------------------- weight transpose->bf16 ---
__global__ __launch_bounds__(256)
void wconv_kernel(const float* __restrict__ in, bf16* __restrict__ out,
                  int R, int C)
{
    __shared__ float t[32][33];
    int c0 = blockIdx.x * 32, r0 = blockIdx.y * 32;
    int tx = threadIdx.x & 31, ty = threadIdx.x >> 5;
    #pragma unroll
    for (int i = 0; i < 4; ++i) {
        int r = r0 + ty + 8 * i;
        if (r < R && c0 + tx < C) t[ty + 8 * i][tx] = in[(long)r * C + c0 + tx];
    }
    __syncthreads();
    #pragma unroll
    for (int i = 0; i < 4; ++i) {
        int c = c0 + ty + 8 * i;
        int r = r0 + tx;
        if (c < C && r < R) out[(long)c * R + r] = __float2bfloat16(t[tx][ty + 8 * i]);
    }
}

// ---------------------------------------------------------------- LayerNorm -
__global__ __launch_bounds__(256)
void ln_kernel(const float* __restrict__ in, long in_stride,
               bf16* __restrict__ out, long out_stride,
               const float* __restrict__ w, const float* __restrict__ b)
{
    long r = blockIdx.x;
    const float* x = in + r * in_stride;
    bf16* y = out + r * out_stride;
    int tid = threadIdx.x;

    float s = 0.f, s2 = 0.f;
    for (int i = tid; i < DIM; i += 256) {
        float v = x[i];
        s += v; s2 += v * v;
    }
    #pragma unroll
    for (int off = 32; off > 0; off >>= 1) {
        s  += __shfl_down(s, off);
        s2 += __shfl_down(s2, off);
    }
    __shared__ float red[2][4];
    int wave = tid >> 6, lane = tid & 63;
    if (lane == 0) { red[0][wave] = s; red[1][wave] = s2; }
    __syncthreads();
    if (tid == 0) {
        float t  = red[0][0] + red[0][1] + red[0][2] + red[0][3];
        float t2 = red[1][0] + red[1][1] + red[1][2] + red[1][3];
        float mean = t / (float)DIM;
        float var  = t2 / (float)DIM - mean * mean;
        red[0][0] = mean;
        red[1][0] = 1.0f / sqrtf(var + 1e-6f);
    }
    __syncthreads();
    float mean = red[0][0], rstd = red[1][0];
    for (int i = tid; i < DIM; i += 256)
        y[i] = __float2bfloat16((x[i] - mean) * rstd * w[i] + b[i]);
}

// ---------------------------------------------------------------- im2col ----
__global__ __launch_bounds__(256)
void im2col_kernel(const float* __restrict__ x, bf16* __restrict__ out)
{
    long i = (long)blockIdx.x * 256 + threadIdx.x;
    const long total = (long)BV * NPAT * DIM;
    if (i >= total) return;
    int col = (int)(i % DIM);
    long row = i / DIM;
    int c  = col >> 8;
    int py = (col >> 4) & 15;
    int px = col & 15;
    int b  = (int)(row / NPAT);
    int pp = (int)(row % NPAT);
    int gy = pp / 14, gx = pp % 14;
    out[i] = __float2bfloat16(
        x[(((long)(b * 3 + c) * 224 + gy * 16 + py) * 224) + gx * 16 + px]);
}

// ---------------------------------------------------------------- assemble --
__global__ __launch_bounds__(256)
void assemble_kernel(const float* __restrict__ tmp, const float* __restrict__ cls,
                     const float* __restrict__ pos, float* __restrict__ h)
{
    long i = (long)blockIdx.x * 256 + threadIdx.x;
    const long total = (long)BV * NSEQ * DIM;
    if (i >= total) return;
    int d = (int)(i % DIM);
    long row = i / DIM;
    int n = (int)(row % NSEQ);
    long b = row / NSEQ;
    float v;
    if (n == 0) v = cls[d];
    else        v = tmp[(b * NPAT + (n - 1)) * DIM + d];
    h[i] = v + pos[(long)n * DIM + d];
}

// ---------------------------------------------------------------- launch ----
extern "C" void kernel_launch(void* const* d_in, const int* in_sizes, int n_in,
                              void* d_out, int out_size, void* d_ws, size_t ws_size,
                              hipStream_t stream)
{
    const float* x        = (const float*)d_in[0];
    const float* patch_w  = (const float*)d_in[1];
    const float* patch_b  = (const float*)d_in[2];
    const float* cls_tok  = (const float*)d_in[3];
    const float* pos_emb  = (const float*)d_in[4];
    const float* ln1_w    = (const float*)d_in[5];
    const float* ln1_b    = (const float*)d_in[6];
    const float* qkv_w    = (const float*)d_in[7];
    const float* qkv_b    = (const float*)d_in[8];
    const float* proj_w   = (const float*)d_in[9];
    const float* proj_b   = (const float*)d_in[10];
    const float* ln2_w    = (const float*)d_in[11];
    const float* ln2_b    = (const float*)d_in[12];
    const float* fc1_w    = (const float*)d_in[13];
    const float* fc1_b    = (const float*)d_in[14];
    const float* fc2_w    = (const float*)d_in[15];
    const float* fc2_b    = (const float*)d_in[16];
    const float* normf_w  = (const float*)d_in[17];
    const float* normf_b  = (const float*)d_in[18];
    const float* head_w   = (const float*)d_in[19];
    const float* head_b   = (const float*)d_in[20];
    float* out = (float*)d_out;

    const long M = (long)BV * NSEQ;   // 6304
    const long MP = (long)BV * NPAT;  // 6272

    // ---- workspace layout ----
    float* h      = (float*)d_ws;                 // [6304][768] fp32
    float* ptmp   = h + 4841472L;                 // patch-embed tmp fp32 [6272][768]
    bf16*  qkv    = (bf16*)(ptmp + 4816896L);     // [6304][2304] bf16
    bf16*  lnout  = qkv + 14524416L;              // [6304][768] bf16 (ln out / O)
    bf16*  big    = lnout + 4841472L;             // [6304][3072] bf16 (patches/mlp)
    bf16*  wT     = big + 19365888L;              // per-layer transposed weights
    bf16*  qkvT = wT;                             // [2304][768]
    bf16*  projT = wT + 1769472L;                 // [768][768]
    bf16*  fc1T  = wT + 2359296L;                 // [3072][768]
    bf16*  fc2T  = wT + 4718592L;                 // [768][3072]

    dim3 blk(256);

    // ---- patch embed ----
    wconv_kernel<<<dim3(24, 24), blk, 0, stream>>>(patch_w, qkvT, DIM, DIM);
    im2col_kernel<<<dim3((unsigned)((MP * DIM + 255) / 256)), blk, 0, stream>>>(x, big);
    bgemm<0, false, float><<<dim3(6, 49), blk, 0, stream>>>(
        big, qkvT, patch_b, ptmp, (int)MP, DIM, DIM, DIM, DIM, DIM);
    assemble_kernel<<<dim3((unsigned)((M * DIM + 255) / 256)), blk, 0, stream>>>(
        ptmp, cls_tok, pos_emb, h);

    // ---- transformer blocks ----
    for (int l = 0; l < NLAYER; ++l) {
        wconv_kernel<<<dim3(72, 24), blk, 0, stream>>>(
            qkv_w + (long)l * DIM * 3 * DIM, qkvT, DIM, 3 * DIM);
        wconv_kernel<<<dim3(24, 24), blk, 0, stream>>>(
            proj_w + (long)l * DIM * DIM, projT, DIM, DIM);
        wconv_kernel<<<dim3(96, 24), blk, 0, stream>>>(
            fc1_w + (long)l * DIM * MLPD, fc1T, DIM, MLPD);
        wconv_kernel<<<dim3(24, 96), blk, 0, stream>>>(
            fc2_w + (long)l * MLPD * DIM, fc2T, MLPD, DIM);

        // LN1: h -> lnout (bf16)
        ln_kernel<<<dim3((unsigned)M), blk, 0, stream>>>(
            h, DIM, lnout, DIM, ln1_w + (long)l * DIM, ln1_b + (long)l * DIM);

        // QKV: lnout @ qkvT^T + qb -> qkv (bf16)
        bgemm<0, false, bf16><<<dim3(18, 50), blk, 0, stream>>>(
            lnout, qkvT, qkv_b + (long)l * 3 * DIM, qkv,
            (int)M, 3 * DIM, DIM, DIM, DIM, 3 * DIM);

        // fused attention -> lnout (bf16 O)
        attn_kernel<<<dim3(4, BV * NHD), blk, 0, stream>>>(qkv, lnout);

        // proj: h += O @ projT^T + pb
        bgemm<0, true, float><<<dim3(6, 50), blk, 0, stream>>>(
            lnout, projT, proj_b + (long)l * DIM, h,
            (int)M, DIM, DIM, DIM, DIM, DIM);

        // LN2: h -> lnout (bf16)
        ln_kernel<<<dim3((unsigned)M), blk, 0, stream>>>(
            h, DIM, lnout, DIM, ln2_w + (long)l * DIM, ln2_b + (long)l * DIM);

        // FC1 + GELU -> big (bf16)
        bgemm<1, false, bf16><<<dim3(24, 50), blk, 0, stream>>>(
            lnout, fc1T, fc1_b + (long)l * MLPD, big,
            (int)M, MLPD, DIM, DIM, DIM, MLPD);

        // FC2: h += big @ fc2T^T + f2b
        bgemm<0, true, float><<<dim3(6, 50), blk, 0, stream>>>(
            big, fc2T, fc2_b + (long)l * DIM, h,
            (int)M, DIM, MLPD, MLPD, MLPD, DIM);
    }

    // ---- final LN on cls rows -> lnout[0:32] (bf16) ----
    ln_kernel<<<dim3(BV), blk, 0, stream>>>(
        h, (long)NSEQ * DIM, lnout, DIM, normf_w, normf_b);

    // ---- head ----
    wconv_kernel<<<dim3(32, 24), blk, 0, stream>>>(head_w, qkvT, DIM, NCLS);
    bgemm<0, false, float><<<dim3(8, 1), blk, 0, stream>>>(
        lnout, qkvT, head_b, out, BV, NCLS, DIM, DIM, DIM, NCLS);
}